// Round 7
// baseline (66.325 us; speedup 1.0000x reference)
//
#include <hip/hip_runtime.h>
#include <math.h>

#define CLIPV 0.03f

struct W9 { float g[9]; };

__device__ __forceinline__ int reflect_idx(int i, int n) {
    if (i < 0) i = -i;
    if (i >= n) i = 2 * n - 2 - i;
    return i;
}

// ---------------------------------------------------------------------------
// Pass A: H-conv only. Zero LDS, zero cross-lane, zero barriers.
// One wave = (z-plane, 16-row h-chunk); lane owns 4 consecutive cols.
// March h with a 9-deep float4 ring of RAW rows (full unroll => static
// indices), 36 FMA per output f4, contiguous 1 KB wave loads/stores.
// Grid: 1024 blocks x 4 waves = 4096 waves (16/CU). bid&7 = XCD owns a
// 32-plane z-band (tmp producer side of the XCD swizzle).
// ---------------------------------------------------------------------------
__global__ __launch_bounds__(256) void h_pass(const float* __restrict__ x,
                                              float* __restrict__ tmp, W9 wt) {
    const int bid = blockIdx.x;
    const int xcd = bid & 7;
    const int k   = bid >> 3;              // 0..127
    const int z   = xcd * 32 + (k >> 2);   // XCD-local z band
    const int q   = k & 3;
    const int wv  = threadIdx.x >> 6;
    const int h0  = (q * 4 + wv) * 16;     // this wave's 16 output rows
    const int w4  = (threadIdx.x & 63) * 4;

    const float* plane  = x   + (size_t)z * 65536;
    float*       oplane = tmp + (size_t)z * 65536;

    float4 ring[9];

    // 2-deep load pipeline
    float4 cur = *(const float4*)(plane + reflect_idx(h0 - 4, 256) * 256 + w4);
    float4 nxt = *(const float4*)(plane + reflect_idx(h0 - 3, 256) * 256 + w4);

    #pragma unroll
    for (int i = 0; i < 24; ++i) {
        float4 nn;
        if (i < 22)
            nn = *(const float4*)(plane + reflect_idx(h0 - 2 + i, 256) * 256 + w4);

        ring[i % 9] = cur;   // raw row h0-4+i (static index after unroll)

        if (i >= 8) {
            float a0 = 0.f, a1 = 0.f, a2 = 0.f, a3 = 0.f;
            #pragma unroll
            for (int j = 0; j < 9; ++j) {
                const float4 v = ring[(i - 8 + j) % 9];
                a0 = fmaf(wt.g[j], v.x, a0);
                a1 = fmaf(wt.g[j], v.y, a1);
                a2 = fmaf(wt.g[j], v.z, a2);
                a3 = fmaf(wt.g[j], v.w, a3);
            }
            float4 o; o.x = a0; o.y = a1; o.z = a2; o.w = a3;
            *(float4*)(oplane + (h0 + i - 8) * 256 + w4) = o;
        }

        cur = nxt; nxt = nn;
    }
}

// ---------------------------------------------------------------------------
// Pass B: W-conv + D-conv + clip, fused. Zero LDS, zero barriers.
// One wave = (row h, 16-plane z-chunk); lane owns 4 consecutive cols.
// Per z-step: 3 overlapping f4 loads of tmp (L1/L2/L3-hot; edge lanes load
// shifted f4 and reverse via selects — validated R5 scheme), W-conv (36 FMA)
// -> 9-deep z-ring -> D-conv (36 FMA) + clip vs x + store.
// Grid: 1024 blocks x 4 waves = 4096 waves (16/CU). Chunk->XCD mapping
// matches pass A's writer band (z-chunk 2*xcd+s).
// ---------------------------------------------------------------------------
__global__ __launch_bounds__(256) void wd_clip_pass(const float* __restrict__ tmp,
                                                    const float* __restrict__ x,
                                                    float* __restrict__ out, W9 wt) {
    const int bid = blockIdx.x;
    const int xcd = bid & 7;
    const int k   = bid >> 3;                       // 0..127
    const int h   = (k >> 1) * 4 + (threadIdx.x >> 6);
    const int z0  = (xcd * 2 + (k & 1)) * 16;       // XCD-local z-chunk
    const int L   = threadIdx.x & 63;
    const int w4  = L * 4;
    const bool l0 = (L == 0), l63 = (L == 63);
    // lane 0: cols -4..-1 reflect-> 4,3,2,1: load f4 at 1, use reversed.
    // lane 63: cols 256..259 reflect-> 254..251: load f4 at 251, reversed.
    const int offL = l0 ? 1 : (w4 - 4);
    const int offR = l63 ? 251 : (w4 + 4);

    const size_t rowoff = (size_t)h * 256;

    float4 ring[9];

    #pragma unroll
    for (int i = 0; i < 24; ++i) {
        const int zr = reflect_idx(z0 - 4 + i, 256);
        const float* trow = tmp + (size_t)zr * 65536 + rowoff;
        const float4 Lf = *(const float4*)(trow + offL);
        const float4 Cf = *(const float4*)(trow + w4);
        const float4 Rf = *(const float4*)(trow + offR);

        // issue the clip-source load early (hides under W-conv)
        const int z = z0 + i - 8;
        float4 xv;
        if (i >= 8)
            xv = *(const float4*)(x + (size_t)z * 65536 + rowoff + w4);

        float sv[12];
        sv[0] = l0 ? Lf.w : Lf.x;   // col -4 -> 4
        sv[1] = l0 ? Lf.z : Lf.y;   // col -3 -> 3
        sv[2] = l0 ? Lf.y : Lf.z;   // col -2 -> 2
        sv[3] = l0 ? Lf.x : Lf.w;   // col -1 -> 1
        sv[4] = Cf.x; sv[5] = Cf.y; sv[6] = Cf.z; sv[7] = Cf.w;
        sv[8]  = l63 ? Rf.w : Rf.x; // col 256 -> 254
        sv[9]  = l63 ? Rf.z : Rf.y; // col 257 -> 253
        sv[10] = l63 ? Rf.y : Rf.z; // col 258 -> 252
        sv[11] = l63 ? Rf.x : Rf.w; // col 259 -> 251

        // W-conv -> one float4 (this z-plane)
        float4 wc;
        {
            float a0 = 0.f, a1 = 0.f, a2 = 0.f, a3 = 0.f;
            #pragma unroll
            for (int j = 0; j < 9; ++j) {
                a0 = fmaf(wt.g[j], sv[j],     a0);
                a1 = fmaf(wt.g[j], sv[j + 1], a1);
                a2 = fmaf(wt.g[j], sv[j + 2], a2);
                a3 = fmaf(wt.g[j], sv[j + 3], a3);
            }
            wc.x = a0; wc.y = a1; wc.z = a2; wc.w = a3;
        }
        ring[i % 9] = wc;   // static index after unroll

        // D-conv + clip + store
        if (i >= 8) {
            float a0 = 0.f, a1 = 0.f, a2 = 0.f, a3 = 0.f;
            #pragma unroll
            for (int j = 0; j < 9; ++j) {
                const float4 v = ring[(i - 8 + j) % 9];
                a0 = fmaf(wt.g[j], v.x, a0);
                a1 = fmaf(wt.g[j], v.y, a1);
                a2 = fmaf(wt.g[j], v.z, a2);
                a3 = fmaf(wt.g[j], v.w, a3);
            }
            float4 r;
            r.x = fmaxf(fminf(xv.x, a0 + CLIPV), a0 - CLIPV);
            r.y = fmaxf(fminf(xv.y, a1 + CLIPV), a1 - CLIPV);
            r.z = fmaxf(fminf(xv.z, a2 + CLIPV), a2 - CLIPV);
            r.w = fmaxf(fminf(xv.w, a3 + CLIPV), a3 - CLIPV);
            *(float4*)(out + (size_t)z * 65536 + rowoff + w4) = r;
        }
    }
}

extern "C" void kernel_launch(void* const* d_in, const int* in_sizes, int n_in,
                              void* d_out, int out_size, void* d_ws, size_t ws_size,
                              hipStream_t stream) {
    const float* x = (const float*)d_in[0];
    float* out = (float*)d_out;
    float* tmp = (float*)d_ws;   // 64 MB

    // normalized 1-D Gaussian weights (separable form of the reference kernel)
    W9 wt;
    {
        double g[9], s = 0.0;
        const double sigma = 9.0 / 4.0;
        for (int i = 0; i < 9; ++i) {
            double tt = (i - 4.0) / sigma;
            g[i] = exp(-0.5 * tt * tt);
            s += g[i];
        }
        for (int i = 0; i < 9; ++i) wt.g[i] = (float)(g[i] / s);
    }

    h_pass<<<dim3(1024), dim3(256), 0, stream>>>(x, tmp, wt);
    wd_clip_pass<<<dim3(1024), dim3(256), 0, stream>>>(tmp, x, out, wt);
}